// Round 5
// baseline (87.286 us; speedup 1.0000x reference)
//
#include <hip/hip_runtime.h>
#include <cstdint>
#include <cstddef>

// ---- problem constants ----
static constexpr int BATCH = 32;
static constexpr int CIN   = 3;
static constexpr int HIN   = 224, WIN = 224;
static constexpr int COUT  = 64;
static constexpr int HOUT  = 56, WOUT = 56;
static constexpr int NPIX  = HOUT * WOUT;     // 3136 = 49*64
static constexpr int NEXP  = 8;
static constexpr int PH    = 227;             // padded rows: 3 zero rows on top
static constexpr int PW    = 232;             // 3 left pad + 224 + 5 right pad
static constexpr int KROWS = 21;              // ci*7 + kh
static constexpr int KPAD2 = 192;             // 24 rows * 8 slots
static constexpr int NKS   = 6;               // K-steps of 32
static constexpr float LN_EPS_F = 1e-6f;

typedef __bf16 bf16x8 __attribute__((ext_vector_type(8)));
typedef float  f32x4  __attribute__((ext_vector_type(4)));

// ---- device-global scratch ----
__device__ __align__(16) ushort g_xbf[BATCH * CIN * PH * PW];  // padded bf16 x (~10.1 MB)
__device__ __align__(16) ushort g_pw2[9 * COUT * KPAD2];       // bf16 weights, k' layout
__device__ float g_gateinp[BATCH * CIN];

__device__ __forceinline__ ushort f2bf(float f) {
  uint u = __float_as_uint(f);
  uint r = (u + 0x7FFFu + ((u >> 16) & 1u)) >> 16;             // RNE
  return (ushort)r;
}

// ---------------- kernel 1: fused pad+convert+gate_mean (0..95) / repack (96..527) ----
__global__ __launch_bounds__(256) void k_pre(const float* __restrict__ x,
                                             const float* __restrict__ eW,
                                             const float* __restrict__ sW) {
  const int bid = blockIdx.x;
  if (bid < BATCH * CIN) {
    // one (image, channel) plane: write padded bf16 + accumulate gate sum
    const float* __restrict__ src = x + (size_t)bid * (HIN * WIN);
    uint* __restrict__ dst = reinterpret_cast<uint*>(g_xbf + (size_t)bid * (PH * PW));
    float s = 0.f;
    for (int i = threadIdx.x; i < PH * (PW / 2); i += 256) {
      const int r = i / (PW / 2);
      const int j = i - r * (PW / 2);
      uint o = 0u;
      if (r >= 3) {  // rows 0..2 are zero padding
        const int ih = r - 3;
        const int c0 = 2 * j - 3;   // input col for padded col 2j
        const int c1 = 2 * j - 2;   // input col for padded col 2j+1
        float f0 = ((unsigned)c0 < (unsigned)WIN) ? src[ih * WIN + c0] : 0.f;
        float f1 = ((unsigned)c1 < (unsigned)WIN) ? src[ih * WIN + c1] : 0.f;
        s += f0 + f1;               // each input element appears exactly once
        o = (uint)f2bf(f0) | ((uint)f2bf(f1) << 16);
      }
      dst[i] = o;
    }
    __shared__ float red[256];
    red[threadIdx.x] = s;
    __syncthreads();
    for (int off = 128; off > 0; off >>= 1) {
      if ((int)threadIdx.x < off) red[threadIdx.x] += red[threadIdx.x + off];
      __syncthreads();
    }
    if (threadIdx.x == 0) g_gateinp[bid] = red[0] * (1.f / (float)(HIN * WIN));
  } else {
    // repack weights -> bf16 [9][64][192], k' = (ci*7+kh)*8 + kw, kw=7 & row>=21 zero
    const int idx = (bid - BATCH * CIN) * 256 + threadIdx.x;
    if (idx >= 9 * COUT * KPAD2) return;
    const int k2  = idx % KPAD2;
    const int coe = idx / KPAD2;    // e*64 + co
    const int co  = coe & 63;
    const int e   = coe >> 6;
    const int kw  = k2 & 7;
    const int row = k2 >> 3;
    float v = 0.f;
    if (kw < 7 && row < KROWS) {
      const int k = row * 7 + kw;
      v = (e < 8) ? eW[(size_t)coe * 147 + k] : sW[(size_t)co * 147 + k];
    }
    g_pw2[idx] = f2bf(v);
  }
}

// ---------------- kernel 2: MFMA conv + LN + gated combine (+gating +loss) ----------
// Block: 1 image x 64 pixels, 4 waves; wave w owns co slice [16w,16w+16).
// B-fragments load directly from padded global bf16 image (no LDS staging).
__global__ __launch_bounds__(256) void k_main(
    const float* __restrict__ w_gate,
    const float* __restrict__ eB, const float* __restrict__ sB,
    const float* __restrict__ elnw, const float* __restrict__ elnb,
    const float* __restrict__ slnw, const float* __restrict__ slnb,
    float* __restrict__ out, float* __restrict__ loss_out) {
  __shared__ float2 Sstats[4 * 3 * 4 * 16];   // [wave][expert][cb][col] (6 KB)

  const int tid  = threadIdx.x;
  const int lane = tid & 63;
  const int w    = tid >> 6;
  const int b    = blockIdx.x / (NPIX / 64);
  const int t    = blockIdx.x % (NPIX / 64);
  const int t64  = t * 64;

  // ---- gating for this image (uniform across all lanes) ----
  const float gi0 = g_gateinp[b * 3 + 0];
  const float gi1 = g_gateinp[b * 3 + 1];
  const float gi2 = g_gateinp[b * 3 + 2];
  float best1 = -1e30f, best2 = -1e30f;
  int i1 = 0, i2 = 0;
  #pragma unroll
  for (int e = 0; e < NEXP; ++e) {
    const float lg = gi0 * w_gate[e] + gi1 * w_gate[8 + e] + gi2 * w_gate[16 + e];
    if (lg > best1) { best2 = best1; i2 = i1; best1 = lg; i1 = e; }
    else if (lg > best2) { best2 = lg; i2 = e; }
  }
  const float e21 = expf(best2 - best1);
  const float g1 = 1.f / (1.f + e21);
  const float g2 = e21 / (1.f + e21);
  const int e1 = __builtin_amdgcn_readfirstlane(i1);
  const int e2 = __builtin_amdgcn_readfirstlane(i2);

  // ---- aux loss: block 0, wave 0 (lane = image) ----
  if (blockIdx.x == 0 && w == 0) {
    float mg1 = 0.f, mg2 = 0.f;
    int me1 = -1, me2 = -1;
    if (lane < BATCH) {
      const float a0 = g_gateinp[lane * 3 + 0];
      const float a1 = g_gateinp[lane * 3 + 1];
      const float a2 = g_gateinp[lane * 3 + 2];
      float b1 = -1e30f, b2 = -1e30f;
      int j1 = 0, j2 = 0;
      #pragma unroll
      for (int e = 0; e < NEXP; ++e) {
        const float lg = a0 * w_gate[e] + a1 * w_gate[8 + e] + a2 * w_gate[16 + e];
        if (lg > b1) { b2 = b1; j2 = j1; b1 = lg; j1 = e; }
        else if (lg > b2) { b2 = lg; j2 = e; }
      }
      const float q = expf(b2 - b1);
      mg1 = 1.f / (1.f + q); mg2 = q / (1.f + q);
      me1 = j1; me2 = j2;
    }
    float imp[NEXP], lod[NEXP];
    #pragma unroll
    for (int e = 0; e < NEXP; ++e) {
      float ie = ((me1 == e) ? mg1 : 0.f) + ((me2 == e) ? mg2 : 0.f);
      float le = (((me1 == e) && (mg1 > 0.f)) ? 1.f : 0.f)
               + (((me2 == e) && (mg2 > 0.f)) ? 1.f : 0.f);
      #pragma unroll
      for (int o = 32; o > 0; o >>= 1) { ie += __shfl_xor(ie, o, 64); le += __shfl_xor(le, o, 64); }
      imp[e] = ie; lod[e] = le;
    }
    if (lane == 0) {
      float mi = 0.f, ml = 0.f;
      #pragma unroll
      for (int e = 0; e < NEXP; ++e) { mi += imp[e]; ml += lod[e]; }
      mi *= (1.f / NEXP); ml *= (1.f / NEXP);
      float vi = 0.f, vl = 0.f;
      #pragma unroll
      for (int e = 0; e < NEXP; ++e) {
        const float di = imp[e] - mi; vi += di * di;
        const float dl = lod[e] - ml; vl += dl * dl;
      }
      vi *= (1.f / (NEXP - 1)); vl *= (1.f / (NEXP - 1));
      loss_out[0] = 0.01f * (vi / (mi * mi + 1e-10f) + vl / (ml * ml + 1e-10f));
    }
  }

  // ---- per-lane address precompute ----
  const int m    = lane >> 4;        // k-chunk index (0..3)
  const int colA = lane & 15;        // A: co row / B: pixel col
  const ushort* __restrict__ bimg = g_xbf + (size_t)b * (CIN * PH * PW);

  int pbase[4];
  #pragma unroll
  for (int cb = 0; cb < 4; ++cb) {
    const int pg = t64 + cb * 16 + colA;
    const int oh = pg / WOUT;
    const int ow = pg - oh * WOUT;
    pbase[cb] = (oh * 4) * PW + ow * 4;      // padded coords: ih' = oh*4+kh, col = ow*4+kw
  }
  int offs[NKS];
  #pragma unroll
  for (int ks = 0; ks < NKS; ++ks) {
    int row = ks * 4 + m;
    row = row > 20 ? 20 : row;               // rows 21..23: weights are zero, clamp addr
    const int ci = row >= 14 ? 2 : (row >= 7 ? 1 : 0);
    const int kh = row - ci * 7;
    offs[ks] = (ci * PH + kh) * PW;
  }

  const int wbase = w * 16;
  const int eidx[3] = {e1, e2, 8};
  const ushort* __restrict__ ap[3];
  #pragma unroll
  for (int e = 0; e < 3; ++e)
    ap[e] = g_pw2 + ((size_t)(eidx[e] * COUT + wbase + colA)) * KPAD2 + m * 8;

  // ---- MFMA main loop: acc[cb][e] += A_e(ks) * B_cb(ks) ----
  f32x4 acc[4][3];
  #pragma unroll
  for (int cb = 0; cb < 4; ++cb)
    #pragma unroll
    for (int e = 0; e < 3; ++e) acc[cb][e] = (f32x4){0.f, 0.f, 0.f, 0.f};

  #pragma unroll
  for (int ks = 0; ks < NKS; ++ks) {
    bf16x8 af[3];
    #pragma unroll
    for (int e = 0; e < 3; ++e)
      af[e] = __builtin_bit_cast(bf16x8,
          *reinterpret_cast<const uint4*>(ap[e] + ks * 32));
    #pragma unroll
    for (int cb = 0; cb < 4; ++cb) {
      const ushort* bp = bimg + pbase[cb] + offs[ks];
      const uint2 lo = *reinterpret_cast<const uint2*>(bp);      // 8B-aligned
      const uint2 hi = *reinterpret_cast<const uint2*>(bp + 4);
      const uint4 raw = {lo.x, lo.y, hi.x, hi.y};
      const bf16x8 bf = __builtin_bit_cast(bf16x8, raw);
      #pragma unroll
      for (int e = 0; e < 3; ++e)
        acc[cb][e] = __builtin_amdgcn_mfma_f32_16x16x32_bf16(af[e], bf, acc[cb][e], 0, 0, 0);
    }
  }

  // ---- bias + per-pixel LN stats ----
  const int co0 = wbase + m * 4;
  const int col = colA;
  float4 bias[3];
  bias[0] = *reinterpret_cast<const float4*>(eB + e1 * COUT + co0);
  bias[1] = *reinterpret_cast<const float4*>(eB + e2 * COUT + co0);
  bias[2] = *reinterpret_cast<const float4*>(sB + co0);
  #pragma unroll
  for (int cb = 0; cb < 4; ++cb)
    #pragma unroll
    for (int e = 0; e < 3; ++e) {
      acc[cb][e][0] += (&bias[e].x)[0];
      acc[cb][e][1] += (&bias[e].x)[1];
      acc[cb][e][2] += (&bias[e].x)[2];
      acc[cb][e][3] += (&bias[e].x)[3];
    }

  #pragma unroll
  for (int cb = 0; cb < 4; ++cb)
    #pragma unroll
    for (int e = 0; e < 3; ++e) {
      float s = acc[cb][e][0] + acc[cb][e][1] + acc[cb][e][2] + acc[cb][e][3];
      float q = acc[cb][e][0] * acc[cb][e][0] + acc[cb][e][1] * acc[cb][e][1]
              + acc[cb][e][2] * acc[cb][e][2] + acc[cb][e][3] * acc[cb][e][3];
      s += __shfl_xor(s, 16, 64); s += __shfl_xor(s, 32, 64);
      q += __shfl_xor(q, 16, 64); q += __shfl_xor(q, 32, 64);
      if (lane < 16) Sstats[((w * 3 + e) * 4 + cb) * 16 + col] = make_float2(s, q);
    }
  __syncthreads();

  // ---- LN + gated combine + store ----
  float4 lw[3], lb[3];
  lw[0] = *reinterpret_cast<const float4*>(elnw + e1 * COUT + co0);
  lw[1] = *reinterpret_cast<const float4*>(elnw + e2 * COUT + co0);
  lw[2] = *reinterpret_cast<const float4*>(slnw + co0);
  lb[0] = *reinterpret_cast<const float4*>(elnb + e1 * COUT + co0);
  lb[1] = *reinterpret_cast<const float4*>(elnb + e2 * COUT + co0);
  lb[2] = *reinterpret_cast<const float4*>(slnb + co0);
  const float ge[3] = {g1, g2, 1.f};

  float* outb = out + (size_t)b * (COUT * NPIX) + t64;
  #pragma unroll
  for (int cb = 0; cb < 4; ++cb) {
    float u[3], rr[3];
    #pragma unroll
    for (int e = 0; e < 3; ++e) {
      float s = 0.f, q = 0.f;
      #pragma unroll
      for (int ww = 0; ww < 4; ++ww) {
        const float2 sq = Sstats[((ww * 3 + e) * 4 + cb) * 16 + col];
        s += sq.x; q += sq.y;
      }
      u[e] = s * (1.f / 64.f);
      const float var = q * (1.f / 64.f) - u[e] * u[e];
      rr[e] = rsqrtf(var + LN_EPS_F);
    }
    #pragma unroll
    for (int reg = 0; reg < 4; ++reg) {
      float o = 0.f;
      #pragma unroll
      for (int e = 0; e < 3; ++e) {
        const float y = acc[cb][e][reg];
        o += ge[e] * ((&lw[e].x)[reg] * (y - u[e]) * rr[e] + (&lb[e].x)[reg]);
      }
      outb[(size_t)(co0 + reg) * NPIX + cb * 16 + col] = o;
    }
  }
}

// ---------------- launch ----------------
extern "C" void kernel_launch(void* const* d_in, const int* in_sizes, int n_in,
                              void* d_out, int out_size, void* d_ws, size_t ws_size,
                              hipStream_t stream) {
  const float* x    = (const float*)d_in[0];
  const float* eW   = (const float*)d_in[1];
  const float* eB   = (const float*)d_in[2];
  const float* elnw = (const float*)d_in[3];
  const float* elnb = (const float*)d_in[4];
  const float* sW   = (const float*)d_in[5];
  const float* sB   = (const float*)d_in[6];
  const float* slnw = (const float*)d_in[7];
  const float* slnb = (const float*)d_in[8];
  const float* wg   = (const float*)d_in[9];
  float* out = (float*)d_out;

  float* loss_ptr = out + (size_t)BATCH * COUT * NPIX;  // element 6422528

  const int repack_blocks = (9 * COUT * KPAD2 + 255) / 256;  // 432
  k_pre<<<BATCH * CIN + repack_blocks, 256, 0, stream>>>(x, eW, sW);
  k_main<<<BATCH * (NPIX / 64), 256, 0, stream>>>(wg, eB, sB, elnw, elnb,
                                                  slnw, slnb, out, loss_ptr);
}

// Round 6
// 61.546 us; speedup vs baseline: 1.4182x; 1.4182x over previous
//
#include <hip/hip_runtime.h>
#include <cstdint>
#include <cstddef>

// ---- problem constants ----
static constexpr int BATCH = 32;
static constexpr int CIN   = 3;
static constexpr int HIN   = 224, WIN = 224;
static constexpr int COUT  = 64;
static constexpr int HOUT  = 56, WOUT = 56;
static constexpr int NPIX  = HOUT * WOUT;     // 3136 = 49*64
static constexpr int NEXP  = 8;
static constexpr int PH    = 227;             // padded rows: 3 zero rows on top
static constexpr int PW    = 232;             // 3 left pad + 224 + 5 right pad
static constexpr int KROWS = 21;              // ci*7 + kh
static constexpr int KPAD2 = 192;             // 24 rows * 8 slots
static constexpr int NKS   = 6;               // K-steps of 32
static constexpr float LN_EPS_F = 1e-6f;

// k_pre role partition
static constexpr int CONV_SLICES = 16;
static constexpr int ROWS_PER_SLICE = 15;     // 16*15 = 240 >= 227
static constexpr int N_CONV = BATCH * CIN * CONV_SLICES;          // 1536
static constexpr int N_GATE = BATCH * CIN;                        // 96
static constexpr int N_REPACK = (9 * COUT * KPAD2 + 255) / 256;   // 432

typedef __bf16 bf16x8 __attribute__((ext_vector_type(8)));
typedef float  f32x4  __attribute__((ext_vector_type(4)));

// ---- device-global scratch ----
__device__ __align__(16) ushort g_xbf[BATCH * CIN * PH * PW];  // padded bf16 x (~10.1 MB)
__device__ __align__(16) ushort g_pw2[9 * COUT * KPAD2];       // bf16 weights, k' layout
__device__ float g_gateinp[BATCH * CIN];

__device__ __forceinline__ ushort f2bf(float f) {
  uint u = __float_as_uint(f);
  uint r = (u + 0x7FFFu + ((u >> 16) & 1u)) >> 16;             // RNE
  return (ushort)r;
}

// ---------------- kernel 1: fused convert (0..1535) / gate_mean (1536..1631) /
//                             repack (1632..2063) ----------------
__global__ __launch_bounds__(256) void k_pre(const float* __restrict__ x,
                                             const float* __restrict__ eW,
                                             const float* __restrict__ sW) {
  const int bid = blockIdx.x;
  if (bid < N_CONV) {
    // ---- pad + f32->bf16 convert: one 15-row slice of one (b,ci) plane ----
    const int plane = bid / CONV_SLICES;
    const int slice = bid - plane * CONV_SLICES;
    const float* __restrict__ src = x + (size_t)plane * (HIN * WIN);
    uint* __restrict__ dst = reinterpret_cast<uint*>(g_xbf + (size_t)plane * (PH * PW));
    const int i0 = slice * (ROWS_PER_SLICE * (PW / 2));
    const int iN = PH * (PW / 2);
    const int i1 = (i0 + ROWS_PER_SLICE * (PW / 2) < iN) ? i0 + ROWS_PER_SLICE * (PW / 2) : iN;
    for (int i = i0 + (int)threadIdx.x; i < i1; i += 256) {
      const int r = i / (PW / 2);
      const int j = i - r * (PW / 2);
      uint o = 0u;
      if (r >= 3) {                 // rows 0..2 are zero padding
        const int ih = r - 3;
        const int c0 = 2 * j - 3;   // input col for padded col 2j
        const int c1 = 2 * j - 2;   // input col for padded col 2j+1
        const float f0 = ((unsigned)c0 < (unsigned)WIN) ? src[ih * WIN + c0] : 0.f;
        const float f1 = ((unsigned)c1 < (unsigned)WIN) ? src[ih * WIN + c1] : 0.f;
        o = (uint)f2bf(f0) | ((uint)f2bf(f1) << 16);
      }
      dst[i] = o;
    }
  } else if (bid < N_CONV + N_GATE) {
    // ---- gate_inp = mean_{H,W}(x), f32-exact, coalesced float4 ----
    const int plane = bid - N_CONV;
    const float4* p4 = reinterpret_cast<const float4*>(x + (size_t)plane * (HIN * WIN));
    float s = 0.f;
    for (int i = threadIdx.x; i < (HIN * WIN) / 4; i += 256) {
      const float4 v = p4[i];
      s += v.x + v.y + v.z + v.w;
    }
    __shared__ float red[256];
    red[threadIdx.x] = s;
    __syncthreads();
    for (int off = 128; off > 0; off >>= 1) {
      if ((int)threadIdx.x < off) red[threadIdx.x] += red[threadIdx.x + off];
      __syncthreads();
    }
    if (threadIdx.x == 0) g_gateinp[plane] = red[0] * (1.f / (float)(HIN * WIN));
  } else {
    // ---- repack weights -> bf16 [9][64][192], k' = (ci*7+kh)*8 + kw ----
    const int idx = (bid - N_CONV - N_GATE) * 256 + threadIdx.x;
    if (idx >= 9 * COUT * KPAD2) return;
    const int k2  = idx % KPAD2;
    const int coe = idx / KPAD2;    // e*64 + co
    const int co  = coe & 63;
    const int e   = coe >> 6;
    const int kw  = k2 & 7;
    const int row = k2 >> 3;
    float v = 0.f;
    if (kw < 7 && row < KROWS) {
      const int k = row * 7 + kw;
      v = (e < 8) ? eW[(size_t)coe * 147 + k] : sW[(size_t)co * 147 + k];
    }
    g_pw2[idx] = f2bf(v);
  }
}

// ---------------- kernel 2: MFMA conv + LN + gated combine (+gating +loss) ----------
// Block: 1 image x 64 pixels, 4 waves; wave w owns co slice [16w,16w+16).
// B-fragments load directly from padded global bf16 image (no LDS staging).
__global__ __launch_bounds__(256) void k_main(
    const float* __restrict__ w_gate,
    const float* __restrict__ eB, const float* __restrict__ sB,
    const float* __restrict__ elnw, const float* __restrict__ elnb,
    const float* __restrict__ slnw, const float* __restrict__ slnb,
    float* __restrict__ out, float* __restrict__ loss_out) {
  __shared__ float2 Sstats[4 * 3 * 4 * 16];   // [wave][expert][cb][col] (6 KB)

  const int tid  = threadIdx.x;
  const int lane = tid & 63;
  const int w    = tid >> 6;
  const int b    = blockIdx.x / (NPIX / 64);
  const int t    = blockIdx.x % (NPIX / 64);
  const int t64  = t * 64;

  // ---- gating for this image (uniform across all lanes) ----
  const float gi0 = g_gateinp[b * 3 + 0];
  const float gi1 = g_gateinp[b * 3 + 1];
  const float gi2 = g_gateinp[b * 3 + 2];
  float best1 = -1e30f, best2 = -1e30f;
  int i1 = 0, i2 = 0;
  #pragma unroll
  for (int e = 0; e < NEXP; ++e) {
    const float lg = gi0 * w_gate[e] + gi1 * w_gate[8 + e] + gi2 * w_gate[16 + e];
    if (lg > best1) { best2 = best1; i2 = i1; best1 = lg; i1 = e; }
    else if (lg > best2) { best2 = lg; i2 = e; }
  }
  const float e21 = expf(best2 - best1);
  const float g1 = 1.f / (1.f + e21);
  const float g2 = e21 / (1.f + e21);
  const int e1 = __builtin_amdgcn_readfirstlane(i1);
  const int e2 = __builtin_amdgcn_readfirstlane(i2);

  // ---- aux loss: block 0, wave 0 (lane = image) ----
  if (blockIdx.x == 0 && w == 0) {
    float mg1 = 0.f, mg2 = 0.f;
    int me1 = -1, me2 = -1;
    if (lane < BATCH) {
      const float a0 = g_gateinp[lane * 3 + 0];
      const float a1 = g_gateinp[lane * 3 + 1];
      const float a2 = g_gateinp[lane * 3 + 2];
      float b1 = -1e30f, b2 = -1e30f;
      int j1 = 0, j2 = 0;
      #pragma unroll
      for (int e = 0; e < NEXP; ++e) {
        const float lg = a0 * w_gate[e] + a1 * w_gate[8 + e] + a2 * w_gate[16 + e];
        if (lg > b1) { b2 = b1; j2 = j1; b1 = lg; j1 = e; }
        else if (lg > b2) { b2 = lg; j2 = e; }
      }
      const float q = expf(b2 - b1);
      mg1 = 1.f / (1.f + q); mg2 = q / (1.f + q);
      me1 = j1; me2 = j2;
    }
    float imp[NEXP], lod[NEXP];
    #pragma unroll
    for (int e = 0; e < NEXP; ++e) {
      float ie = ((me1 == e) ? mg1 : 0.f) + ((me2 == e) ? mg2 : 0.f);
      float le = (((me1 == e) && (mg1 > 0.f)) ? 1.f : 0.f)
               + (((me2 == e) && (mg2 > 0.f)) ? 1.f : 0.f);
      #pragma unroll
      for (int o = 32; o > 0; o >>= 1) { ie += __shfl_xor(ie, o, 64); le += __shfl_xor(le, o, 64); }
      imp[e] = ie; lod[e] = le;
    }
    if (lane == 0) {
      float mi = 0.f, ml = 0.f;
      #pragma unroll
      for (int e = 0; e < NEXP; ++e) { mi += imp[e]; ml += lod[e]; }
      mi *= (1.f / NEXP); ml *= (1.f / NEXP);
      float vi = 0.f, vl = 0.f;
      #pragma unroll
      for (int e = 0; e < NEXP; ++e) {
        const float di = imp[e] - mi; vi += di * di;
        const float dl = lod[e] - ml; vl += dl * dl;
      }
      vi *= (1.f / (NEXP - 1)); vl *= (1.f / (NEXP - 1));
      loss_out[0] = 0.01f * (vi / (mi * mi + 1e-10f) + vl / (ml * ml + 1e-10f));
    }
  }

  // ---- per-lane address precompute ----
  const int m    = lane >> 4;        // k-chunk index (0..3)
  const int colA = lane & 15;        // A: co row / B: pixel col
  const ushort* __restrict__ bimg = g_xbf + (size_t)b * (CIN * PH * PW);

  int pbase[4];
  #pragma unroll
  for (int cb = 0; cb < 4; ++cb) {
    const int pg = t64 + cb * 16 + colA;
    const int oh = pg / WOUT;
    const int ow = pg - oh * WOUT;
    pbase[cb] = (oh * 4) * PW + ow * 4;      // padded coords: ih' = oh*4+kh, col = ow*4+kw
  }
  int offs[NKS];
  #pragma unroll
  for (int ks = 0; ks < NKS; ++ks) {
    int row = ks * 4 + m;
    row = row > 20 ? 20 : row;               // rows 21..23: weights are zero, clamp addr
    const int ci = row >= 14 ? 2 : (row >= 7 ? 1 : 0);
    const int kh = row - ci * 7;
    offs[ks] = (ci * PH + kh) * PW;
  }

  const int wbase = w * 16;
  const int eidx[3] = {e1, e2, 8};
  const ushort* __restrict__ ap[3];
  #pragma unroll
  for (int e = 0; e < 3; ++e)
    ap[e] = g_pw2 + ((size_t)(eidx[e] * COUT + wbase + colA)) * KPAD2 + m * 8;

  // ---- MFMA main loop: acc[cb][e] += A_e(ks) * B_cb(ks) ----
  f32x4 acc[4][3];
  #pragma unroll
  for (int cb = 0; cb < 4; ++cb)
    #pragma unroll
    for (int e = 0; e < 3; ++e) acc[cb][e] = (f32x4){0.f, 0.f, 0.f, 0.f};

  #pragma unroll
  for (int ks = 0; ks < NKS; ++ks) {
    bf16x8 af[3];
    #pragma unroll
    for (int e = 0; e < 3; ++e)
      af[e] = __builtin_bit_cast(bf16x8,
          *reinterpret_cast<const uint4*>(ap[e] + ks * 32));
    #pragma unroll
    for (int cb = 0; cb < 4; ++cb) {
      const ushort* bp = bimg + pbase[cb] + offs[ks];
      const uint2 lo = *reinterpret_cast<const uint2*>(bp);      // 8B-aligned
      const uint2 hi = *reinterpret_cast<const uint2*>(bp + 4);
      const uint4 raw = {lo.x, lo.y, hi.x, hi.y};
      const bf16x8 bf = __builtin_bit_cast(bf16x8, raw);
      #pragma unroll
      for (int e = 0; e < 3; ++e)
        acc[cb][e] = __builtin_amdgcn_mfma_f32_16x16x32_bf16(af[e], bf, acc[cb][e], 0, 0, 0);
    }
  }

  // ---- bias + per-pixel LN stats ----
  const int co0 = wbase + m * 4;
  const int col = colA;
  float4 bias[3];
  bias[0] = *reinterpret_cast<const float4*>(eB + e1 * COUT + co0);
  bias[1] = *reinterpret_cast<const float4*>(eB + e2 * COUT + co0);
  bias[2] = *reinterpret_cast<const float4*>(sB + co0);
  #pragma unroll
  for (int cb = 0; cb < 4; ++cb)
    #pragma unroll
    for (int e = 0; e < 3; ++e) {
      acc[cb][e][0] += (&bias[e].x)[0];
      acc[cb][e][1] += (&bias[e].x)[1];
      acc[cb][e][2] += (&bias[e].x)[2];
      acc[cb][e][3] += (&bias[e].x)[3];
    }

  #pragma unroll
  for (int cb = 0; cb < 4; ++cb)
    #pragma unroll
    for (int e = 0; e < 3; ++e) {
      float s = acc[cb][e][0] + acc[cb][e][1] + acc[cb][e][2] + acc[cb][e][3];
      float q = acc[cb][e][0] * acc[cb][e][0] + acc[cb][e][1] * acc[cb][e][1]
              + acc[cb][e][2] * acc[cb][e][2] + acc[cb][e][3] * acc[cb][e][3];
      s += __shfl_xor(s, 16, 64); s += __shfl_xor(s, 32, 64);
      q += __shfl_xor(q, 16, 64); q += __shfl_xor(q, 32, 64);
      if (lane < 16) Sstats[((w * 3 + e) * 4 + cb) * 16 + col] = make_float2(s, q);
    }
  __syncthreads();

  // ---- LN + gated combine + store ----
  float4 lw[3], lb[3];
  lw[0] = *reinterpret_cast<const float4*>(elnw + e1 * COUT + co0);
  lw[1] = *reinterpret_cast<const float4*>(elnw + e2 * COUT + co0);
  lw[2] = *reinterpret_cast<const float4*>(slnw + co0);
  lb[0] = *reinterpret_cast<const float4*>(elnb + e1 * COUT + co0);
  lb[1] = *reinterpret_cast<const float4*>(elnb + e2 * COUT + co0);
  lb[2] = *reinterpret_cast<const float4*>(slnb + co0);
  const float ge[3] = {g1, g2, 1.f};

  float* outb = out + (size_t)b * (COUT * NPIX) + t64;
  #pragma unroll
  for (int cb = 0; cb < 4; ++cb) {
    float u[3], rr[3];
    #pragma unroll
    for (int e = 0; e < 3; ++e) {
      float s = 0.f, q = 0.f;
      #pragma unroll
      for (int ww = 0; ww < 4; ++ww) {
        const float2 sq = Sstats[((ww * 3 + e) * 4 + cb) * 16 + col];
        s += sq.x; q += sq.y;
      }
      u[e] = s * (1.f / 64.f);
      const float var = q * (1.f / 64.f) - u[e] * u[e];
      rr[e] = rsqrtf(var + LN_EPS_F);
    }
    #pragma unroll
    for (int reg = 0; reg < 4; ++reg) {
      float o = 0.f;
      #pragma unroll
      for (int e = 0; e < 3; ++e) {
        const float y = acc[cb][e][reg];
        o += ge[e] * ((&lw[e].x)[reg] * (y - u[e]) * rr[e] + (&lb[e].x)[reg]);
      }
      outb[(size_t)(co0 + reg) * NPIX + cb * 16 + col] = o;
    }
  }
}

// ---------------- launch ----------------
extern "C" void kernel_launch(void* const* d_in, const int* in_sizes, int n_in,
                              void* d_out, int out_size, void* d_ws, size_t ws_size,
                              hipStream_t stream) {
  const float* x    = (const float*)d_in[0];
  const float* eW   = (const float*)d_in[1];
  const float* eB   = (const float*)d_in[2];
  const float* elnw = (const float*)d_in[3];
  const float* elnb = (const float*)d_in[4];
  const float* sW   = (const float*)d_in[5];
  const float* sB   = (const float*)d_in[6];
  const float* slnw = (const float*)d_in[7];
  const float* slnb = (const float*)d_in[8];
  const float* wg   = (const float*)d_in[9];
  float* out = (float*)d_out;

  float* loss_ptr = out + (size_t)BATCH * COUT * NPIX;  // element 6422528

  k_pre<<<N_CONV + N_GATE + N_REPACK, 256, 0, stream>>>(x, eW, sW);
  k_main<<<BATCH * (NPIX / 64), 256, 0, stream>>>(wg, eB, sB, elnw, elnb,
                                                  slnw, slnb, out, loss_ptr);
}